// Round 13
// baseline (83.973 us; speedup 1.0000x reference)
//
#include <hip/hip_runtime.h>
#include <hip/hip_bf16.h>

// MMD-RBF: B=4, Ns=Nt=2048 (N=4096 concat), K=32, KERNEL_MUL=2, KERNEL_NUM=5.
// Pass 1: 64-thr blocks: sq-norms + hi/lo bf16 frag precompute + partials; zero quadbuf
// Pass 3: row-segment scheduling: 187 segments/batch, each = up to 3 pairs
//         (bx, by0..by0+2) sharing the A panel. A staged once + A-frags hoisted
//         to registers; B-only LDS double buffer (prefetch->compute->write->bar);
//         per-wave spread atomics (no cross-wave LDS reduce); merged coef reduce.
// Pass 4: separate combine kernel (kernel boundary = coherence), out[b].

#define NPTS 4096   // per batch (2048 src + 2048 tgt)
#define HALF 2048
#define KDIM 32
#define T3   128    // tile dim
#define NTB3 32     // NPTS / T3
#define GRIDX 187   // row-segments per batch (sum over rows of ceil(len/3))
#define SPREAD 64

#define WS_SQ    0          // 4*4096*4   = 65536
#define WS_PART  65536      // 4*64*33*8  = 67584  -> ends 133120
#define WS_QUAD  133120     // 4*4*64*8   = 8192   -> ends 141312
#define WS_FRAG  147456     // 4*4096*128 = 2 MB
#define WS_NEED  (147456 + 4 * NPTS * 128)

typedef __attribute__((ext_vector_type(8))) short short8v;  // 8 bf16 (4 VGPRs)
typedef __attribute__((ext_vector_type(4))) float f32x4;    // C/D frag

__device__ __forceinline__ float fast_exp2(float x) {
#if __has_builtin(__builtin_amdgcn_exp2f)
  return __builtin_amdgcn_exp2f(x);
#else
  return exp2f(x);
#endif
}

__device__ __forceinline__ unsigned int bf16_rne(float x) {
  unsigned int u = __float_as_uint(x);
  return (u + 0x7fffu + ((u >> 16) & 1u)) >> 16;
}

__device__ __forceinline__ const float* point_ptr(const float* __restrict__ src,
                                                  const float* __restrict__ tgt,
                                                  int b, int p) {
  return (p < HALF) ? src + ((size_t)b * HALF + p) * KDIM
                    : tgt + ((size_t)b * HALF + (p - HALF)) * KDIM;
}

// ---- Pass 1: 64-thread blocks, grid (64, 4) --------------------------------
__global__ void __launch_bounds__(64)
mmd_pass1(const float* __restrict__ src, const float* __restrict__ tgt,
          float* __restrict__ sqArr, double* __restrict__ part1,
          double* __restrict__ quadbuf,
          unsigned char* __restrict__ frags, int preFlag) {
  const int b = blockIdx.y;
  const int tid = threadIdx.x;       // 0..63
  const int p = blockIdx.x * 64 + tid;

  if (blockIdx.x == 0) {
#pragma unroll
    for (int i = 0; i < 4; ++i)
      quadbuf[b * 4 * SPREAD + i * 64 + tid] = 0.0;
  }

  const float* __restrict__ xp = point_ptr(src, tgt, b, p);
  float x[KDIM];
#pragma unroll
  for (int q = 0; q < 8; ++q) {
    float4 v = reinterpret_cast<const float4*>(xp)[q];
    x[4*q+0] = v.x; x[4*q+1] = v.y; x[4*q+2] = v.z; x[4*q+3] = v.w;
  }
  float s0 = 0.f, s1 = 0.f, s2 = 0.f, s3 = 0.f;
#pragma unroll
  for (int q = 0; q < 8; ++q) {
    s0 = fmaf(x[4*q+0], x[4*q+0], s0);
    s1 = fmaf(x[4*q+1], x[4*q+1], s1);
    s2 = fmaf(x[4*q+2], x[4*q+2], s2);
    s3 = fmaf(x[4*q+3], x[4*q+3], s3);
  }
  const float sq = (s0 + s1) + (s2 + s3);
  sqArr[(size_t)b * NPTS + p] = sq;

  // hi/lo bf16 fragments: 64 B hi (slots 0-3) + 64 B lo (slots 4-7) per point
  if (preFlag) {
    unsigned int hw[16], lw[16];
#pragma unroll
    for (int e = 0; e < 16; ++e) {
      const float xa = x[2*e], xb = x[2*e+1];
      const unsigned int ha = bf16_rne(xa);
      const unsigned int la = bf16_rne(xa - __uint_as_float(ha << 16));
      const unsigned int hb = bf16_rne(xb);
      const unsigned int lb = bf16_rne(xb - __uint_as_float(hb << 16));
      hw[e] = ha | (hb << 16);
      lw[e] = la | (lb << 16);
    }
    uint4* dst = reinterpret_cast<uint4*>(frags + (size_t)(b * NPTS + p) * 128);
#pragma unroll
    for (int c = 0; c < 4; ++c)
      dst[c] = make_uint4(hw[4*c], hw[4*c+1], hw[4*c+2], hw[4*c+3]);
#pragma unroll
    for (int c = 0; c < 4; ++c)
      dst[4 + c] = make_uint4(lw[4*c], lw[4*c+1], lw[4*c+2], lw[4*c+3]);
  }

  // component sums via LDS transpose (one wave)
  __shared__ float lx[64][KDIM + 1];
#pragma unroll
  for (int k = 0; k < KDIM; ++k) lx[tid][k] = x[k];
  __syncthreads();

  double* slot = part1 + ((size_t)b * 64 + blockIdx.x) * 33;
  if (tid < 32) {
    float ps = 0.f;
#pragma unroll 16
    for (int r = 0; r < 64; ++r) ps += lx[r][tid];
    slot[1 + tid] = (double)ps;
  }
  float w = sq;
#pragma unroll
  for (int off = 32; off > 0; off >>= 1) w += __shfl_down(w, off, 64);
  if (tid == 0) slot[0] = (double)w;
}

// LDS fragment read: logical slot = half*4 + lk, stored XOR-swizzled by point
__device__ __forceinline__ short8v lds_frag(const unsigned char* base, int p,
                                            int half, int lk) {
  const int slot = (half * 4 + lk) ^ (p & 7);
  return *reinterpret_cast<const short8v*>(base + p * 128 + slot * 16);
}

// ---- Pass 3: row-segment persistent MFMA Gram + fused epilogue -------------
template <bool PRE>
__global__ void __launch_bounds__(512, 6)
mmd_pass3(const float* __restrict__ src, const float* __restrict__ tgt,
          const float* __restrict__ sqArr, const double* __restrict__ part1,
          const unsigned char* __restrict__ frags,
          double* __restrict__ quadbuf) {
  const int bid = blockIdx.x;          // 0..186 row-segment index
  const int b = blockIdx.y;
  const int tid = threadIdx.x;         // 512 = 8 waves
  const int lane = tid & 63;
  const int w = tid >> 6;
  const int lm = lane & 15;
  const int lk = lane >> 4;
  const int wr = w & 3;                // wave row-group (32 rows)
  const int wc = w >> 2;               // wave col-group (64 cols)

  // decode segment -> (bx, by0, cnt): row bx has pairs by = bx..31,
  // chopped into segments of 3
  int rem = bid, bx = 0;
  for (;;) {
    const int nseg = (32 - bx + 2) / 3;
    if (rem < nseg) break;
    rem -= nseg; ++bx;
  }
  const int by0 = bx + rem * 3;
  const int cnt = min(3, 32 - by0);

  __shared__ __align__(16) unsigned char fragA[T3 * 128];     // 16 KB
  __shared__ __align__(16) unsigned char fragB[2][T3 * 128];  // 32 KB
  __shared__ float s_sqA[T3], s_sqB[2][T3];
  __shared__ double red[33];
  __shared__ float s_nc4;

  const float* __restrict__ sqG = sqArr + (size_t)b * NPTS;
  const uint4* __restrict__ gfr =
      reinterpret_cast<const uint4*>(frags) + (size_t)b * NPTS * 8;

  // ---- merged pass2: bandwidth coefficient (redundant per block) ----
  if (tid < 33) {
    double s = 0.0;
#pragma unroll 16
    for (int blk = 0; blk < 64; ++blk)
      s += part1[((size_t)b * 64 + blk) * 33 + tid];
    red[tid] = s;
  }
  __syncthreads();
  if (tid == 0) {
    double ssq = red[0], s2 = 0.0;
    for (int k = 1; k <= 32; ++k) s2 += red[k] * red[k];
    const double N = (double)NPTS;
    double bw = (2.0 * N * ssq - 2.0 * s2) / (N * N - N + 1e-8);
    bw *= 0.25;  // / KERNEL_MUL^(KERNEL_NUM//2)
    s_nc4 = (float)(-1.4426950408889634 / (bw * 16.0));  // widest bandwidth (t=4)
  }

  // ---- stage A panel (once) + B panel for by0 ----
  if constexpr (PRE) {
#pragma unroll
    for (int i = 0; i < 2; ++i) {
      const int g = tid + i * 512;       // p = g>>3, s = g&7
      const int p = g >> 3, s = g & 7;
      const int d = p * 8 + (s ^ (p & 7));
      reinterpret_cast<uint4*>(fragA)[d] = gfr[(size_t)bx * 1024 + g];
      reinterpret_cast<uint4*>(fragB[0])[d] = gfr[(size_t)by0 * 1024 + g];
    }
  } else if (tid < 256) {
    const int pt = tid & 127;
    const bool isB = tid >= 128;
    const float* fp = point_ptr(src, tgt, b, (isB ? by0 : bx) * T3 + pt);
    unsigned int hw[16], lw[16];
#pragma unroll
    for (int e = 0; e < 16; ++e) {
      const float xa = fp[2*e], xb = fp[2*e+1];
      const unsigned int ha = bf16_rne(xa);
      const unsigned int la = bf16_rne(xa - __uint_as_float(ha << 16));
      const unsigned int hb = bf16_rne(xb);
      const unsigned int lb = bf16_rne(xb - __uint_as_float(hb << 16));
      hw[e] = ha | (hb << 16);
      lw[e] = la | (lb << 16);
    }
    uint4* dst = reinterpret_cast<uint4*>((isB ? fragB[0] : fragA) + pt * 128);
#pragma unroll
    for (int s = 0; s < 8; ++s) {
      const unsigned int* s4 = (s < 4) ? &hw[s * 4] : &lw[(s - 4) * 4];
      dst[s ^ (pt & 7)] = make_uint4(s4[0], s4[1], s4[2], s4[3]);
    }
  }
  if (tid < 128) s_sqA[tid] = sqG[bx * T3 + tid];
  else if (tid < 256) s_sqB[0][tid - 128] = sqG[by0 * T3 + (tid - 128)];
  __syncthreads();   // A, B0, s_nc4 visible

  const float nc4 = s_nc4;
  const float m2nc = -2.0f * nc4;

  // ---- hoist A fragments + row-sq into registers (constant across pairs) ----
  short8v Ah[2], Al[2];
  float sin_[2][4];
#pragma unroll
  for (int rg = 0; rg < 2; ++rg) {
    const int pa = wr * 32 + rg * 16 + lm;
    Ah[rg] = lds_frag(fragA, pa, 0, lk);
    Al[rg] = lds_frag(fragA, pa, 1, lk);
    const float4 q4 = *reinterpret_cast<const float4*>(
        &s_sqA[wr * 32 + rg * 16 + lk * 4]);
    sin_[rg][0] = q4.x * nc4; sin_[rg][1] = q4.y * nc4;
    sin_[rg][2] = q4.z * nc4; sin_[rg][3] = q4.w * nc4;
  }

  const int rh = (bx >= NTB3 / 2) ? 1 : 0;

  for (int it = 0; it < cnt; ++it) {
    const int c = it & 1;
    const int by = by0 + it;

    // prefetch next B panel into registers (issue-early / write-late)
    uint4 pv0, pv1;
    float nsq = 0.f;
    const bool hn = (it + 1 < cnt);
    if (hn) {
      if constexpr (PRE) {
        pv0 = gfr[(size_t)(by + 1) * 1024 + tid];
        pv1 = gfr[(size_t)(by + 1) * 1024 + tid + 512];
      }
      if (tid < 128) nsq = sqG[(by + 1) * T3 + tid];
    }

    // ---- compute pair (bx, by) from fragA regs + fragB[c] ----
    double accd = 0.0;
#pragma unroll
    for (int cg = 0; cg < 4; ++cg) {
      const int pb = wc * 64 + cg * 16 + lm;
      const short8v Bh = lds_frag(fragB[c], pb, 0, lk);
      const short8v Bl = lds_frag(fragB[c], pb, 1, lk);
      const float sjn = s_sqB[c][pb] * nc4;
#pragma unroll
      for (int rg = 0; rg < 2; ++rg) {
        f32x4 accP = {0.f, 0.f, 0.f, 0.f};
        f32x4 accQ = {0.f, 0.f, 0.f, 0.f};
        accP = __builtin_amdgcn_mfma_f32_16x16x32_bf16(Ah[rg], Bh, accP, 0, 0, 0);
        accQ = __builtin_amdgcn_mfma_f32_16x16x32_bf16(Ah[rg], Bl, accQ, 0, 0, 0);
        accP = __builtin_amdgcn_mfma_f32_16x16x32_bf16(Al[rg], Bl, accP, 0, 0, 0);
        accQ = __builtin_amdgcn_mfma_f32_16x16x32_bf16(Al[rg], Bh, accQ, 0, 0, 0);
        float rs = 0.f;
#pragma unroll
        for (int reg = 0; reg < 4; ++reg) {
          const float dot = accP[reg] + accQ[reg];
          const float arg = fmaf(dot, m2nc, sin_[rg][reg] + sjn);
          float e = fast_exp2(arg);          // widest bandwidth
          float s = e;
          e *= e; s += e;                    // e3
          e *= e; s += e;                    // e2
          e *= e; s += e;                    // e1
          e *= e; s += e;                    // e0
          rs += s;
        }
        accd += (double)rs;
      }
    }

    // per-wave reduce + spread atomics (no cross-wave LDS reduce)
#pragma unroll
    for (int off = 32; off > 0; off >>= 1) accd += __shfl_down(accd, off, 64);
    if (lane == 0) {
      const int ch = (by >= NTB3 / 2) ? 1 : 0;
      const int q  = (rh << 1) | ch;
      const int qT = (ch << 1) | rh;
      const int slot = (bid * 8 + w) & (SPREAD - 1);
      atomicAdd(&quadbuf[(((b << 2) | q) * SPREAD) + slot], accd);
      if (bx != by)
        atomicAdd(&quadbuf[(((b << 2) | qT) * SPREAD) + slot], accd);
    }

    // write prefetched B panel into the other buffer
    if (hn) {
      if constexpr (PRE) {
        {
          const int p = tid >> 3, s = tid & 7;
          reinterpret_cast<uint4*>(fragB[c ^ 1])[p * 8 + (s ^ (p & 7))] = pv0;
        }
        {
          const int g = tid + 512;
          const int p = g >> 3, s = g & 7;
          reinterpret_cast<uint4*>(fragB[c ^ 1])[p * 8 + (s ^ (p & 7))] = pv1;
        }
      } else if (tid < 128) {
        const int pt = tid;
        const float* fp = point_ptr(src, tgt, b, (by + 1) * T3 + pt);
        unsigned int hw[16], lw[16];
#pragma unroll
        for (int e = 0; e < 16; ++e) {
          const float xa = fp[2*e], xb = fp[2*e+1];
          const unsigned int ha = bf16_rne(xa);
          const unsigned int la = bf16_rne(xa - __uint_as_float(ha << 16));
          const unsigned int hb = bf16_rne(xb);
          const unsigned int lb = bf16_rne(xb - __uint_as_float(hb << 16));
          hw[e] = ha | (hb << 16);
          lw[e] = la | (lb << 16);
        }
        uint4* dst = reinterpret_cast<uint4*>(fragB[c ^ 1] + pt * 128);
#pragma unroll
        for (int s = 0; s < 8; ++s) {
          const unsigned int* s4 = (s < 4) ? &hw[s * 4] : &lw[(s - 4) * 4];
          dst[s ^ (pt & 7)] = make_uint4(s4[0], s4[1], s4[2], s4[3]);
        }
      }
      if (tid < 128) s_sqB[c ^ 1][tid] = nsq;
      __syncthreads();   // next buffer ready (single barrier per pair)
    }
  }
}

// ---- Pass 4: final combine (kernel boundary gives coherence) ---------------
__global__ void mmd_pass4(const double* __restrict__ quadbuf, float* __restrict__ out) {
  const int tid = threadIdx.x;  // 256
  const int qq = tid >> 6, i = tid & 63;
  __shared__ double wsum[4];
  const double inv = 1.0 / ((double)HALF * (double)HALF);
  for (int b = 0; b < 4; ++b) {
    double v = quadbuf[((b << 2) | qq) * SPREAD + i];
    double sv = (qq == 0 || qq == 3) ? v : -v;
#pragma unroll
    for (int off = 32; off > 0; off >>= 1) sv += __shfl_down(sv, off, 64);
    if ((tid & 63) == 0) wsum[qq] = sv;
    __syncthreads();
    if (tid == 0) out[b] = (float)((wsum[0] + wsum[1] + wsum[2] + wsum[3]) * inv);
    __syncthreads();
  }
}

extern "C" void kernel_launch(void* const* d_in, const int* in_sizes, int n_in,
                              void* d_out, int out_size, void* d_ws, size_t ws_size,
                              hipStream_t stream) {
  const float* src = (const float*)d_in[0];
  const float* tgt = (const float*)d_in[1];
  float* out = (float*)d_out;

  char* ws = (char*)d_ws;
  float*         sqArr   = (float*)(ws + WS_SQ);
  double*        part1   = (double*)(ws + WS_PART);
  double*        quadbuf = (double*)(ws + WS_QUAD);
  unsigned char* frags   = (unsigned char*)(ws + WS_FRAG);

  const int pre = (ws_size >= (size_t)WS_NEED) ? 1 : 0;

  mmd_pass1<<<dim3(64, 4), 64, 0, stream>>>(src, tgt, sqArr, part1,
                                            quadbuf, frags, pre);
  if (pre)
    mmd_pass3<true><<<dim3(GRIDX, 4), 512, 0, stream>>>(src, tgt, sqArr, part1,
                                                        frags, quadbuf);
  else
    mmd_pass3<false><<<dim3(GRIDX, 4), 512, 0, stream>>>(src, tgt, sqArr, part1,
                                                         frags, quadbuf);
  mmd_pass4<<<1, 256, 0, stream>>>(quadbuf, out);
}